// Round 3
// baseline (340.568 us; speedup 1.0000x reference)
//
#include <hip/hip_runtime.h>

#define EPSF 1e-6f

// dims (fixed for this problem)
#define NB 8
#define LL 4096
#define NHD 8
#define DD 64
#define ROWSTR 512            // H*D
#define NSTR (LL * ROWSTR)    // per-batch stride = 2097152

// workspace float offsets
#define OFF_QSUM 0
#define OFF_KSUM 4096
#define OFF_QNSUM 8192
#define OFF_KNSUM 12288
#define OFF_MX 16384
#define OFF_KV 16448
#define OFF_NCRAW (OFF_KV + 262144)   // 278592
#define OFF_Z (OFF_NCRAW + 262144)    // 540736

__device__ __forceinline__ float sigf(float x) {
  return 1.0f / (1.0f + __expf(-x));
}

__device__ __forceinline__ float rsum16(float p) {
  p += __shfl_xor(p, 1, 16);
  p += __shfl_xor(p, 2, 16);
  p += __shfl_xor(p, 4, 16);
  p += __shfl_xor(p, 8, 16);
  return p;
}

// ---------------- K1: q_sum / k_sum of sigmoid ----------------
__global__ __launch_bounds__(256) void k_sigsum(const float* __restrict__ q,
                                                const float* __restrict__ k,
                                                float* __restrict__ ws) {
  int bid = blockIdx.x;
  const bool isK = bid >= 4096;
  const float* __restrict__ src = isK ? k : q;
  float* __restrict__ dst = ws + (isK ? OFF_KSUM : OFF_QSUM);
  int id = bid & 4095;
  int nh = id >> 6, chunk = id & 63;
  int n = nh >> 3, h = nh & 7;
  int t = threadIdx.x, tq = t & 15, g = t >> 4;
  const float* base = src + (size_t)n * NSTR + h * DD + tq * 4;
  float4 acc = make_float4(0.f, 0.f, 0.f, 0.f);
  int l0 = chunk * 64 + g;
#pragma unroll
  for (int it = 0; it < 4; ++it) {
    const float4 x = *(const float4*)(base + (size_t)(l0 + it * 16) * ROWSTR);
    acc.x += sigf(x.x); acc.y += sigf(x.y); acc.z += sigf(x.z); acc.w += sigf(x.w);
  }
  __shared__ float4 red[256];
  red[t] = acc;
  __syncthreads();
  for (int s = 128; s >= 16; s >>= 1) {
    if (t < s) {
      float4 o = red[t + s];
      float4 m = red[t];
      m.x += o.x; m.y += o.y; m.z += o.z; m.w += o.w;
      red[t] = m;
    }
    __syncthreads();
  }
  if (t < 16) {
    float4 vv = red[t];
    float* dp = dst + nh * 64 + t * 4;
    atomicAdd(dp + 0, vv.x); atomicAdd(dp + 1, vv.y);
    atomicAdd(dp + 2, vv.z); atomicAdd(dp + 3, vv.w);
  }
}

// ---------------- K2: qn_sum / kn_sum with on-the-fly normalizers ----------------
__global__ __launch_bounds__(256) void k_stage1(const float* __restrict__ q,
                                                const float* __restrict__ k,
                                                float* __restrict__ ws) {
  int bid = blockIdx.x;
  const bool isK = bid >= 4096;
  const float* __restrict__ src = isK ? k : q;
  const float* __restrict__ vsr = ws + (isK ? OFF_QSUM : OFF_KSUM);
  float* __restrict__ dst = ws + (isK ? OFF_KNSUM : OFF_QNSUM);
  int id = bid & 4095;
  int nh = id >> 6, chunk = id & 63;
  int n = nh >> 3, h = nh & 7;
  int t = threadIdx.x, tq = t & 15, g = t >> 4;
  __shared__ float vec[64];
  if (t < 64) vec[t] = vsr[nh * 64 + t] + EPSF;
  __syncthreads();
  const float4 ve = *(const float4*)&vec[tq * 4];
  const float* base = src + (size_t)n * NSTR + h * DD + tq * 4;
  float4 acc = make_float4(0.f, 0.f, 0.f, 0.f);
  int l0 = chunk * 64 + g;
#pragma unroll
  for (int it = 0; it < 4; ++it) {
    const float4 x = *(const float4*)(base + (size_t)(l0 + it * 16) * ROWSTR);
    float4 s;
    s.x = sigf(x.x); s.y = sigf(x.y); s.z = sigf(x.z); s.w = sigf(x.w);
    float p = (s.x + EPSF) * ve.x + (s.y + EPSF) * ve.y +
              (s.z + EPSF) * ve.z + (s.w + EPSF) * ve.w;
    p = rsum16(p);
    float nrm = 1.0f / p;
    acc.x += s.x * nrm; acc.y += s.y * nrm; acc.z += s.z * nrm; acc.w += s.w * nrm;
  }
  __shared__ float4 red[256];
  red[t] = acc;
  __syncthreads();
  for (int s = 128; s >= 16; s >>= 1) {
    if (t < s) {
      float4 o = red[t + s];
      float4 m = red[t];
      m.x += o.x; m.y += o.y; m.z += o.z; m.w += o.w;
      red[t] = m;
    }
    __syncthreads();
  }
  if (t < 16) {
    float4 vv = red[t];
    float* dp = dst + nh * 64 + t * 4;
    atomicAdd(dp + 0, vv.x); atomicAdd(dp + 1, vv.y);
    atomicAdd(dp + 2, vv.z); atomicAdd(dp + 3, vv.w);
  }
}

// ---------------- K3: nc_raw + per-(n,h) max ----------------
__global__ __launch_bounds__(256) void k_ncraw(const float* __restrict__ k,
                                               float* __restrict__ ws) {
  int bid = blockIdx.x;  // 4096
  int nh = bid >> 6, chunk = bid & 63;
  int n = nh >> 3, h = nh & 7;
  int t = threadIdx.x, tq = t & 15, g = t >> 4;
  __shared__ float vec[64];
  if (t < 64) vec[t] = ws[OFF_QNSUM + nh * 64 + t] + EPSF;
  __syncthreads();
  const float4 ve = *(const float4*)&vec[tq * 4];
  const float* base = k + (size_t)n * NSTR + h * DD + tq * 4;
  float* ncp = ws + OFF_NCRAW + nh * LL;
  float mloc = 0.0f;
  int s0 = chunk * 64 + g;
#pragma unroll
  for (int it = 0; it < 4; ++it) {
    int srow = s0 + it * 16;
    const float4 x = *(const float4*)(base + (size_t)srow * ROWSTR);
    float p = (sigf(x.x) + EPSF) * ve.x + (sigf(x.y) + EPSF) * ve.y +
              (sigf(x.z) + EPSF) * ve.z + (sigf(x.w) + EPSF) * ve.w;
    p = rsum16(p);
    if (tq == 0) ncp[srow] = p;
    mloc = fmaxf(mloc, p);
  }
  __shared__ float red[256];
  red[t] = mloc;
  __syncthreads();
  for (int s = 128; s >= 1; s >>= 1) {
    if (t < s) red[t] = fmaxf(red[t], red[t + s]);
    __syncthreads();
  }
  if (t == 0)
    atomicMax((unsigned int*)(ws + OFF_MX) + nh, __float_as_uint(red[0]));
}

// ---------------- K3b: softmax denominator Z per (n,h) ----------------
__global__ __launch_bounds__(256) void k_softz(float* __restrict__ ws) {
  int nh = blockIdx.x, t = threadIdx.x;
  float mx = __uint_as_float(((unsigned int*)(ws + OFF_MX))[nh]);
  const float* nc = ws + OFF_NCRAW + nh * LL;
  float sum = 0.f;
  for (int i = t; i < LL; i += 256) sum += __expf(nc[i] - mx);
  __shared__ float red[256];
  red[t] = sum;
  __syncthreads();
  for (int s = 128; s >= 1; s >>= 1) {
    if (t < s) red[t] += red[t + s];
    __syncthreads();
  }
  if (t == 0) ws[OFF_Z + nh] = red[0];
}

// ---------------- K4: kv[d][e] = sum_s (sig(k)*w)[s,d] * v[s,e] ----------------
union SmKV {
  float stage[4][2][8][72];  // [wave][k/v][row][64+pad]
  float kvs[64][64];
};

__global__ __launch_bounds__(256) void k_kv(const float* __restrict__ k,
                                            const float* __restrict__ v,
                                            float* __restrict__ ws) {
  int bid = blockIdx.x;  // 512
  int nh = bid >> 3, chunk = bid & 7;
  int n = nh >> 3, h = nh & 7;
  int t = threadIdx.x;
  int w = t >> 6, lane = t & 63;
  float mx = __uint_as_float(((unsigned int*)(ws + OFF_MX))[nh]);
  float scale = (float)LL / ws[OFF_Z + nh];
  __shared__ SmKV sm;
  const float* kbase = k + (size_t)n * NSTR + h * DD;
  const float* vbase = v + (size_t)n * NSTR + h * DD;
  const float* ncr = ws + OFF_NCRAW + nh * LL;
  float acc[8][8];
#pragma unroll
  for (int i = 0; i < 8; ++i)
#pragma unroll
    for (int j = 0; j < 8; ++j) acc[i][j] = 0.f;
  const int d8 = (lane >> 3) * 8, e8 = (lane & 7) * 8;
  const int s0 = chunk * 512 + w * 128;
  for (int it = 0; it < 16; ++it) {
#pragma unroll
    for (int i = 0; i < 4; ++i) {
      int idx = i * 64 + lane;
      int r = idx >> 5, half = (idx >> 4) & 1, tq = idx & 15;
      int srow = s0 + it * 8 + r;
      if (half == 0) {
        const float4 x = *(const float4*)(kbase + (size_t)srow * ROWSTR + tq * 4);
        float wgt = __expf(ncr[srow] - mx) * scale;
        *(float4*)&sm.stage[w][0][r][tq * 4] =
            make_float4(sigf(x.x) * wgt, sigf(x.y) * wgt, sigf(x.z) * wgt, sigf(x.w) * wgt);
      } else {
        const float4 x = *(const float4*)(vbase + (size_t)srow * ROWSTR + tq * 4);
        *(float4*)&sm.stage[w][1][r][tq * 4] = x;
      }
    }
    __syncthreads();
#pragma unroll
    for (int r = 0; r < 8; ++r) {
      float ka[8], va[8];
      *(float4*)&ka[0] = *(const float4*)&sm.stage[w][0][r][d8];
      *(float4*)&ka[4] = *(const float4*)&sm.stage[w][0][r][d8 + 4];
      *(float4*)&va[0] = *(const float4*)&sm.stage[w][1][r][e8];
      *(float4*)&va[4] = *(const float4*)&sm.stage[w][1][r][e8 + 4];
#pragma unroll
      for (int i = 0; i < 8; ++i)
#pragma unroll
        for (int j = 0; j < 8; ++j) acc[i][j] += ka[i] * va[j];
    }
    __syncthreads();
  }
  // cross-wave reduce into sm.kvs (stage buffers dead now; union reuse)
  for (int ww = 0; ww < 4; ++ww) {
    if (w == ww) {
#pragma unroll
      for (int i = 0; i < 8; ++i)
#pragma unroll
        for (int j = 0; j < 8; ++j) {
          if (ww == 0) sm.kvs[d8 + i][e8 + j] = acc[i][j];
          else sm.kvs[d8 + i][e8 + j] += acc[i][j];
        }
    }
    __syncthreads();
  }
  float* kvp = ws + OFF_KV + nh * 4096;
  const float* flat = &sm.kvs[0][0];
#pragma unroll
  for (int i = 0; i < 16; ++i) atomicAdd(&kvp[t * 16 + i], flat[t * 16 + i]);
}

// ---------------- K5: out = (sig(q) . kv) * nrow * nr ----------------
__global__ __launch_bounds__(256) void k_out(const float* __restrict__ q,
                                             float* __restrict__ out,
                                             const float* __restrict__ ws) {
  int bid = blockIdx.x;  // 2048
  int nh = bid >> 5, chunk = bid & 31;
  int n = nh >> 3, h = nh & 7;
  int t = threadIdx.x, tq = t & 15, g = t >> 4;
  __shared__ float kvs[64][64];
  __shared__ float sq[128][72];
  __shared__ float ksv[64], knv[64];
  {
    const float4* kvg = (const float4*)(ws + OFF_KV + (size_t)nh * 4096);
    float4* kvd = (float4*)&kvs[0][0];
#pragma unroll
    for (int i = 0; i < 4; ++i) kvd[i * 256 + t] = kvg[i * 256 + t];
    if (t < 64) {
      ksv[t] = ws[OFF_KSUM + nh * 64 + t] + EPSF;
      knv[t] = ws[OFF_KNSUM + nh * 64 + t] + EPSF;
    }
  }
  __syncthreads();
  const float4 ke = *(const float4*)&ksv[tq * 4];
  const float4 kne = *(const float4*)&knv[tq * 4];
  const float* qbase = q + (size_t)n * NSTR + h * DD + tq * 4;
  float scl[8];
  int l0 = chunk * 128;
#pragma unroll
  for (int rr = 0; rr < 8; ++rr) {
    int row = g + rr * 16;
    const float4 x = *(const float4*)(qbase + (size_t)(l0 + row) * ROWSTR);
    float4 s;
    s.x = sigf(x.x); s.y = sigf(x.y); s.z = sigf(x.z); s.w = sigf(x.w);
    *(float4*)&sq[row][tq * 4] = s;
    float p1 = (s.x + EPSF) * ke.x + (s.y + EPSF) * ke.y +
               (s.z + EPSF) * ke.z + (s.w + EPSF) * ke.w;
    float p2 = (s.x + EPSF) * kne.x + (s.y + EPSF) * kne.y +
               (s.z + EPSF) * kne.z + (s.w + EPSF) * kne.w;
    p1 = rsum16(p1);
    p2 = rsum16(p2);
    scl[rr] = (1.0f / p1) * sigf(p2);  // L/S == 1
  }
  __syncthreads();
  float acc[8][4];
#pragma unroll
  for (int rr = 0; rr < 8; ++rr) {
    acc[rr][0] = 0.f; acc[rr][1] = 0.f; acc[rr][2] = 0.f; acc[rr][3] = 0.f;
  }
  for (int d = 0; d < 64; ++d) {
    const float4 kq = *(const float4*)&kvs[d][tq * 4];
#pragma unroll
    for (int rr = 0; rr < 8; ++rr) {
      float sv = sq[g + rr * 16][d];
      acc[rr][0] += sv * kq.x; acc[rr][1] += sv * kq.y;
      acc[rr][2] += sv * kq.z; acc[rr][3] += sv * kq.w;
    }
  }
  float* obase = out + (size_t)n * NSTR + h * DD + tq * 4;
#pragma unroll
  for (int rr = 0; rr < 8; ++rr) {
    int l = l0 + g + rr * 16;
    float4 o;
    o.x = acc[rr][0] * scl[rr]; o.y = acc[rr][1] * scl[rr];
    o.z = acc[rr][2] * scl[rr]; o.w = acc[rr][3] * scl[rr];
    *(float4*)(obase + (size_t)l * ROWSTR) = o;
  }
}

extern "C" void kernel_launch(void* const* d_in, const int* in_sizes, int n_in,
                              void* d_out, int out_size, void* d_ws, size_t ws_size,
                              hipStream_t stream) {
  const float* q = (const float*)d_in[0];
  const float* k = (const float*)d_in[1];
  const float* v = (const float*)d_in[2];
  float* out = (float*)d_out;
  float* ws = (float*)d_ws;

  // zero accumulators: sums, mx, kv  (nc_raw / Z are fully overwritten)
  hipMemsetAsync(d_ws, 0, (size_t)OFF_NCRAW * sizeof(float), stream);

  hipLaunchKernelGGL(k_sigsum, dim3(8192), dim3(256), 0, stream, q, k, ws);
  hipLaunchKernelGGL(k_stage1, dim3(8192), dim3(256), 0, stream, q, k, ws);
  hipLaunchKernelGGL(k_ncraw, dim3(4096), dim3(256), 0, stream, k, ws);
  hipLaunchKernelGGL(k_softz, dim3(64), dim3(256), 0, stream, ws);
  hipLaunchKernelGGL(k_kv, dim3(512), dim3(256), 0, stream, k, v, ws);
  hipLaunchKernelGGL(k_out, dim3(2048), dim3(256), 0, stream, q, out, ws);
}

// Round 4
// 219.476 us; speedup vs baseline: 1.5517x; 1.5517x over previous
//
#include <hip/hip_runtime.h>

#define EPSF 1e-6f

// dims (fixed for this problem)
#define NB 8
#define LL 4096
#define NHD 8
#define DD 64
#define ROWSTR 512            // H*D
#define NSTR (LL * ROWSTR)    // per-batch stride = 2097152

// workspace float offsets
#define OFF_QSUM 0
#define OFF_KSUM 4096
#define OFF_QNSUM 8192
#define OFF_KNSUM 12288
#define OFF_MX 16384
#define OFF_KV 16448
#define OFF_NCRAW (OFF_KV + 262144)   // 278592
#define OFF_Z (OFF_NCRAW + 262144)    // 540736
#define OFF_KVP (OFF_Z + 64)          // 540800
#define KVP_FLOATS (64 * 16 * 4096)   // 4194304 (16.8 MB of partial kv tiles)

__device__ __forceinline__ float sigf(float x) {
  return 1.0f / (1.0f + __expf(-x));
}

__device__ __forceinline__ float rsum16(float p) {
  p += __shfl_xor(p, 1, 16);
  p += __shfl_xor(p, 2, 16);
  p += __shfl_xor(p, 4, 16);
  p += __shfl_xor(p, 8, 16);
  return p;
}

// ---------------- K1: q_sum / k_sum of sigmoid ----------------
__global__ __launch_bounds__(256) void k_sigsum(const float* __restrict__ q,
                                                const float* __restrict__ k,
                                                float* __restrict__ ws) {
  int bid = blockIdx.x;
  const bool isK = bid >= 4096;
  const float* __restrict__ src = isK ? k : q;
  float* __restrict__ dst = ws + (isK ? OFF_KSUM : OFF_QSUM);
  int id = bid & 4095;
  int nh = id >> 6, chunk = id & 63;
  int n = nh >> 3, h = nh & 7;
  int t = threadIdx.x, tq = t & 15, g = t >> 4;
  const float* base = src + (size_t)n * NSTR + h * DD + tq * 4;
  float4 acc = make_float4(0.f, 0.f, 0.f, 0.f);
  int l0 = chunk * 64 + g;
#pragma unroll
  for (int it = 0; it < 4; ++it) {
    const float4 x = *(const float4*)(base + (size_t)(l0 + it * 16) * ROWSTR);
    acc.x += sigf(x.x); acc.y += sigf(x.y); acc.z += sigf(x.z); acc.w += sigf(x.w);
  }
  __shared__ float4 red[256];
  red[t] = acc;
  __syncthreads();
  for (int s = 128; s >= 16; s >>= 1) {
    if (t < s) {
      float4 o = red[t + s];
      float4 m = red[t];
      m.x += o.x; m.y += o.y; m.z += o.z; m.w += o.w;
      red[t] = m;
    }
    __syncthreads();
  }
  if (t < 16) {
    float4 vv = red[t];
    float* dp = dst + nh * 64 + t * 4;
    atomicAdd(dp + 0, vv.x); atomicAdd(dp + 1, vv.y);
    atomicAdd(dp + 2, vv.z); atomicAdd(dp + 3, vv.w);
  }
}

// ---------------- K2: qn_sum / kn_sum with on-the-fly normalizers ----------------
__global__ __launch_bounds__(256) void k_stage1(const float* __restrict__ q,
                                                const float* __restrict__ k,
                                                float* __restrict__ ws) {
  int bid = blockIdx.x;
  const bool isK = bid >= 4096;
  const float* __restrict__ src = isK ? k : q;
  const float* __restrict__ vsr = ws + (isK ? OFF_QSUM : OFF_KSUM);
  float* __restrict__ dst = ws + (isK ? OFF_KNSUM : OFF_QNSUM);
  int id = bid & 4095;
  int nh = id >> 6, chunk = id & 63;
  int n = nh >> 3, h = nh & 7;
  int t = threadIdx.x, tq = t & 15, g = t >> 4;
  __shared__ float vec[64];
  if (t < 64) vec[t] = vsr[nh * 64 + t] + EPSF;
  __syncthreads();
  const float4 ve = *(const float4*)&vec[tq * 4];
  const float* base = src + (size_t)n * NSTR + h * DD + tq * 4;
  float4 acc = make_float4(0.f, 0.f, 0.f, 0.f);
  int l0 = chunk * 64 + g;
#pragma unroll
  for (int it = 0; it < 4; ++it) {
    const float4 x = *(const float4*)(base + (size_t)(l0 + it * 16) * ROWSTR);
    float4 s;
    s.x = sigf(x.x); s.y = sigf(x.y); s.z = sigf(x.z); s.w = sigf(x.w);
    float p = (s.x + EPSF) * ve.x + (s.y + EPSF) * ve.y +
              (s.z + EPSF) * ve.z + (s.w + EPSF) * ve.w;
    p = rsum16(p);
    float nrm = 1.0f / p;
    acc.x += s.x * nrm; acc.y += s.y * nrm; acc.z += s.z * nrm; acc.w += s.w * nrm;
  }
  __shared__ float4 red[256];
  red[t] = acc;
  __syncthreads();
  for (int s = 128; s >= 16; s >>= 1) {
    if (t < s) {
      float4 o = red[t + s];
      float4 m = red[t];
      m.x += o.x; m.y += o.y; m.z += o.z; m.w += o.w;
      red[t] = m;
    }
    __syncthreads();
  }
  if (t < 16) {
    float4 vv = red[t];
    float* dp = dst + nh * 64 + t * 4;
    atomicAdd(dp + 0, vv.x); atomicAdd(dp + 1, vv.y);
    atomicAdd(dp + 2, vv.z); atomicAdd(dp + 3, vv.w);
  }
}

// ---------------- K3: nc_raw + per-(n,h) max ----------------
__global__ __launch_bounds__(256) void k_ncraw(const float* __restrict__ k,
                                               float* __restrict__ ws) {
  int bid = blockIdx.x;  // 4096
  int nh = bid >> 6, chunk = bid & 63;
  int n = nh >> 3, h = nh & 7;
  int t = threadIdx.x, tq = t & 15, g = t >> 4;
  __shared__ float vec[64];
  if (t < 64) vec[t] = ws[OFF_QNSUM + nh * 64 + t] + EPSF;
  __syncthreads();
  const float4 ve = *(const float4*)&vec[tq * 4];
  const float* base = k + (size_t)n * NSTR + h * DD + tq * 4;
  float* ncp = ws + OFF_NCRAW + nh * LL;
  float mloc = 0.0f;
  int s0 = chunk * 64 + g;
#pragma unroll
  for (int it = 0; it < 4; ++it) {
    int srow = s0 + it * 16;
    const float4 x = *(const float4*)(base + (size_t)srow * ROWSTR);
    float p = (sigf(x.x) + EPSF) * ve.x + (sigf(x.y) + EPSF) * ve.y +
              (sigf(x.z) + EPSF) * ve.z + (sigf(x.w) + EPSF) * ve.w;
    p = rsum16(p);
    if (tq == 0) ncp[srow] = p;
    mloc = fmaxf(mloc, p);
  }
  __shared__ float red[256];
  red[t] = mloc;
  __syncthreads();
  for (int s = 128; s >= 1; s >>= 1) {
    if (t < s) red[t] = fmaxf(red[t], red[t + s]);
    __syncthreads();
  }
  if (t == 0)
    atomicMax((unsigned int*)(ws + OFF_MX) + nh, __float_as_uint(red[0]));
}

// ---------------- K3b: softmax denominator Z per (n,h) ----------------
__global__ __launch_bounds__(256) void k_softz(float* __restrict__ ws) {
  int nh = blockIdx.x, t = threadIdx.x;
  float mx = __uint_as_float(((unsigned int*)(ws + OFF_MX))[nh]);
  const float* nc = ws + OFF_NCRAW + nh * LL;
  float sum = 0.f;
  for (int i = t; i < LL; i += 256) sum += __expf(nc[i] - mx);
  __shared__ float red[256];
  red[t] = sum;
  __syncthreads();
  for (int s = 128; s >= 1; s >>= 1) {
    if (t < s) red[t] += red[t + s];
    __syncthreads();
  }
  if (t == 0) ws[OFF_Z + nh] = red[0];
}

// ---------------- K4: kv[d][e] = sum_s (sig(k)*w)[s,d] * v[s,e] ----------------
// Barrier-free shuffle outer product: lane l holds k[s][l], v[s][l];
// 8x8 per-lane tile gathered via 16 __shfl per row. No LDS in main loop.
__global__ __launch_bounds__(256) void k_kv(const float* __restrict__ k,
                                            const float* __restrict__ v,
                                            float* __restrict__ ws,
                                            int partial) {
  int bid = blockIdx.x;  // 1024
  int nh = bid >> 4, chunk = bid & 15;
  int n = nh >> 3, h = nh & 7;
  int t = threadIdx.x;
  int w = t >> 6, lane = t & 63;
  float mx = __uint_as_float(((unsigned int*)(ws + OFF_MX))[nh]);
  float scale = (float)LL / ws[OFF_Z + nh];
  const float* kbase = k + (size_t)n * NSTR + h * DD;
  const float* vbase = v + (size_t)n * NSTR + h * DD;
  const float* ncr = ws + OFF_NCRAW + nh * LL;

  const int s0 = chunk * 256 + w * 64;  // this wave's 64 rows
  // preload this wave's 64 softmax weights: lane r holds wgt for row s0+r
  float wgt_own = __expf(ncr[s0 + lane] - mx) * scale;

  const int d8 = (lane >> 3) * 8, e8 = (lane & 7) * 8;
  float acc[8][8];
#pragma unroll
  for (int i = 0; i < 8; ++i)
#pragma unroll
    for (int j = 0; j < 8; ++j) acc[i][j] = 0.f;

  const float* kp = kbase + (size_t)s0 * ROWSTR + lane;
  const float* vp = vbase + (size_t)s0 * ROWSTR + lane;
#pragma unroll 2
  for (int r = 0; r < 64; ++r) {
    float kvr = kp[(size_t)r * ROWSTR];
    float vvr = vp[(size_t)r * ROWSTR];
    float wk = sigf(kvr) * __shfl(wgt_own, r, 64);
    float ka[8], va[8];
#pragma unroll
    for (int i = 0; i < 8; ++i) {
      ka[i] = __shfl(wk, d8 + i, 64);
      va[i] = __shfl(vvr, e8 + i, 64);
    }
#pragma unroll
    for (int i = 0; i < 8; ++i)
#pragma unroll
      for (int j = 0; j < 8; ++j) acc[i][j] += ka[i] * va[j];
  }

  // cross-wave reduce, lane-linear LDS layout (stride 65 -> <=2-way, free)
  __shared__ float buf[64 * 65];
  for (int ww = 0; ww < 4; ++ww) {
    if (w == ww) {
#pragma unroll
      for (int ii = 0; ii < 64; ++ii) {
        int off = lane * 65 + ii;
        float val = acc[ii >> 3][ii & 7];
        if (ww == 0) buf[off] = val;
        else buf[off] += val;
      }
    }
    __syncthreads();
  }

  // write out: thread t handles laneslot l = t&63, 16 values
  int l = t & 63, idx0 = (t >> 6) * 16;
  int dl = (l >> 3) * 8, el = (l & 7) * 8;
  if (partial) {
    float* dst = ws + OFF_KVP + (size_t)bid * 4096;
#pragma unroll
    for (int ii = 0; ii < 16; ++ii) {
      int idx = idx0 + ii;
      int d = dl + (idx >> 3), e = el + (idx & 7);
      dst[d * 64 + e] = buf[l * 65 + idx];
    }
  } else {
    float* kvp = ws + OFF_KV + nh * 4096;
#pragma unroll
    for (int ii = 0; ii < 16; ++ii) {
      int idx = idx0 + ii;
      int d = dl + (idx >> 3), e = el + (idx & 7);
      atomicAdd(&kvp[d * 64 + e], buf[l * 65 + idx]);
    }
  }
}

// ---------------- K4b: reduce 16 partial kv tiles per nh ----------------
__global__ __launch_bounds__(256) void k_kvred(float* __restrict__ ws) {
  int f = blockIdx.x * 256 + threadIdx.x;  // 0..65535 float4 index
  int nh = f >> 10, off = f & 1023;
  const float4* src = (const float4*)(ws + OFF_KVP);
  float4 s = make_float4(0.f, 0.f, 0.f, 0.f);
#pragma unroll
  for (int c = 0; c < 16; ++c) {
    float4 x = src[(size_t)((nh * 16 + c) << 10) + off];
    s.x += x.x; s.y += x.y; s.z += x.z; s.w += x.w;
  }
  ((float4*)(ws + OFF_KV))[f] = s;
}

// ---------------- K5: out = (sig(q) . kv) * nrow * nr ----------------
__global__ __launch_bounds__(256) void k_out(const float* __restrict__ q,
                                             float* __restrict__ out,
                                             const float* __restrict__ ws) {
  int bid = blockIdx.x;  // 2048
  int nh = bid >> 5, chunk = bid & 31;
  int n = nh >> 3, h = nh & 7;
  int t = threadIdx.x, tq = t & 15, g = t >> 4;
  __shared__ float kvs[64][64];
  __shared__ float sq[128][72];
  __shared__ float ksv[64], knv[64];
  {
    const float4* kvg = (const float4*)(ws + OFF_KV + (size_t)nh * 4096);
    float4* kvd = (float4*)&kvs[0][0];
#pragma unroll
    for (int i = 0; i < 4; ++i) kvd[i * 256 + t] = kvg[i * 256 + t];
    if (t < 64) {
      ksv[t] = ws[OFF_KSUM + nh * 64 + t] + EPSF;
      knv[t] = ws[OFF_KNSUM + nh * 64 + t] + EPSF;
    }
  }
  __syncthreads();
  const float4 ke = *(const float4*)&ksv[tq * 4];
  const float4 kne = *(const float4*)&knv[tq * 4];
  const float* qbase = q + (size_t)n * NSTR + h * DD + tq * 4;
  float scl[8];
  int l0 = chunk * 128;
#pragma unroll
  for (int rr = 0; rr < 8; ++rr) {
    int row = g + rr * 16;
    const float4 x = *(const float4*)(qbase + (size_t)(l0 + row) * ROWSTR);
    float4 s;
    s.x = sigf(x.x); s.y = sigf(x.y); s.z = sigf(x.z); s.w = sigf(x.w);
    *(float4*)&sq[row][tq * 4] = s;
    float p1 = (s.x + EPSF) * ke.x + (s.y + EPSF) * ke.y +
               (s.z + EPSF) * ke.z + (s.w + EPSF) * ke.w;
    float p2 = (s.x + EPSF) * kne.x + (s.y + EPSF) * kne.y +
               (s.z + EPSF) * kne.z + (s.w + EPSF) * kne.w;
    p1 = rsum16(p1);
    p2 = rsum16(p2);
    scl[rr] = (1.0f / p1) * sigf(p2);  // L/S == 1
  }
  __syncthreads();
  float acc[8][4];
#pragma unroll
  for (int rr = 0; rr < 8; ++rr) {
    acc[rr][0] = 0.f; acc[rr][1] = 0.f; acc[rr][2] = 0.f; acc[rr][3] = 0.f;
  }
  for (int d = 0; d < 64; ++d) {
    const float4 kq = *(const float4*)&kvs[d][tq * 4];
#pragma unroll
    for (int rr = 0; rr < 8; ++rr) {
      float sv = sq[g + rr * 16][d];
      acc[rr][0] += sv * kq.x; acc[rr][1] += sv * kq.y;
      acc[rr][2] += sv * kq.z; acc[rr][3] += sv * kq.w;
    }
  }
  float* obase = out + (size_t)n * NSTR + h * DD + tq * 4;
#pragma unroll
  for (int rr = 0; rr < 8; ++rr) {
    int l = l0 + g + rr * 16;
    float4 o;
    o.x = acc[rr][0] * scl[rr]; o.y = acc[rr][1] * scl[rr];
    o.z = acc[rr][2] * scl[rr]; o.w = acc[rr][3] * scl[rr];
    *(float4*)(obase + (size_t)l * ROWSTR) = o;
  }
}

extern "C" void kernel_launch(void* const* d_in, const int* in_sizes, int n_in,
                              void* d_out, int out_size, void* d_ws, size_t ws_size,
                              hipStream_t stream) {
  const float* q = (const float*)d_in[0];
  const float* k = (const float*)d_in[1];
  const float* v = (const float*)d_in[2];
  float* out = (float*)d_out;
  float* ws = (float*)d_ws;

  // partial-tile path needs ~18.9 MB of ws; fall back to atomics otherwise
  const int partial = (ws_size >= (size_t)(OFF_KVP + KVP_FLOATS) * sizeof(float)) ? 1 : 0;

  // zero accumulators: sums, mx, kv  (nc_raw / Z / kvp are fully overwritten)
  hipMemsetAsync(d_ws, 0, (size_t)OFF_NCRAW * sizeof(float), stream);

  hipLaunchKernelGGL(k_sigsum, dim3(8192), dim3(256), 0, stream, q, k, ws);
  hipLaunchKernelGGL(k_stage1, dim3(8192), dim3(256), 0, stream, q, k, ws);
  hipLaunchKernelGGL(k_ncraw, dim3(4096), dim3(256), 0, stream, k, ws);
  hipLaunchKernelGGL(k_softz, dim3(64), dim3(256), 0, stream, ws);
  hipLaunchKernelGGL(k_kv, dim3(1024), dim3(256), 0, stream, k, v, ws, partial);
  if (partial) hipLaunchKernelGGL(k_kvred, dim3(256), dim3(256), 0, stream, ws);
  hipLaunchKernelGGL(k_out, dim3(2048), dim3(256), 0, stream, q, out, ws);
}